// Round 13
// baseline (118.246 us; speedup 1.0000x reference)
//
#include <hip/hip_runtime.h>

#define NN 50000
#define EE 800000
#define ETOT (EE + NN)
#define MAXD 64      // max degree on fast path (Poisson(16)+1 -> max ~45)
#define NBK 196      // dst buckets of 256 nodes
#define CAP 6144     // records per bucket slot (mean 4352)
#define CHX 2304     // edges per xcast block (9*256); 391 blocks cover ETOT
#define AGW 2        // waves per aggz block

typedef _Float16 f16x8 __attribute__((ext_vector_type(8)));
typedef _Float16 f16x2 __attribute__((ext_vector_type(2)));
typedef float f32x4 __attribute__((ext_vector_type(4)));
typedef float f32x2 __attribute__((ext_vector_type(2)));
typedef unsigned int u32x4 __attribute__((ext_vector_type(4)));

__device__ __forceinline__ float lrelu(float v) { return v > 0.f ? v : 0.2f * v; }
__device__ __forceinline__ unsigned int pack2(float a, float b) {
  unsigned short lo = __builtin_bit_cast(unsigned short, (_Float16)a);
  unsigned short hi = __builtin_bit_cast(unsigned short, (_Float16)b);
  return (unsigned int)lo | ((unsigned int)hi << 16);
}

// ---------------------------------------------------------------------------
// Prep: Bt[col][k] fp16 (k = h*128+c), folded attention WaS/WaD, zero bcnt.
// ---------------------------------------------------------------------------
__global__ void k_prep(const float* __restrict__ W,
                       const float* __restrict__ att_s,
                       const float* __restrict__ att_d,
                       unsigned short* __restrict__ Bt,
                       float* __restrict__ WaS, float* __restrict__ WaD,
                       int* __restrict__ bcnt) {
  int gid = blockIdx.x * blockDim.x + threadIdx.x;
  if (gid < NBK) bcnt[gid] = 0;
  if (gid < 128 * 512) {
    int col = gid >> 9, k = gid & 511;
    float v = W[(k & 127) * 512 + (k >> 7) * 128 + col];
    _Float16 hv = (_Float16)v;
    Bt[col * 512 + k] = __builtin_bit_cast(unsigned short, hv);
  }
  if (gid < 512) {
    int k = gid >> 2, h = gid & 3;
    const float* wrow = W + k * 512 + h * 128;
    const float* as = att_s + h * 128;
    const float* ad = att_d + h * 128;
    float ss = 0.f, sd = 0.f;
    for (int c = 0; c < 128; ++c) { float w = wrow[c]; ss += w * as[c]; sd += w * ad[c]; }
    WaS[k * 4 + h] = ss;
    WaD[k * 4 + h] = sd;
  }
}

// ---------------------------------------------------------------------------
// Fused: x->fp16 xh, pass-1 coarse binning (spread over all blocks), then
// a_s/a_d dot products reading x straight from global (L2-warm).
// ---------------------------------------------------------------------------
__global__ __launch_bounds__(256) void k_xcast_p1(const float* __restrict__ x,
                                                  const float* __restrict__ WaS,
                                                  const float* __restrict__ WaD,
                                                  const int* __restrict__ ei,
                                                  unsigned int* __restrict__ xh,
                                                  float* __restrict__ a_s,
                                                  float* __restrict__ a_d,
                                                  int* __restrict__ bcnt,
                                                  unsigned int* __restrict__ ebuf) {
  __shared__ float4 wsl[128];
  __shared__ float4 wdl[128];
  __shared__ int cnt[NBK];
  __shared__ int gbase[NBK];
  int t = threadIdx.x;
  int nb = blockIdx.x * 128;
  if (t < 128) wsl[t] = ((const float4*)WaS)[t];
  else wdl[t - 128] = ((const float4*)WaD)[t - 128];
  for (int i = t; i < NBK; i += 256) cnt[i] = 0;

  // ---- phase 1: x -> fp16 xh (streaming, no LDS)
#pragma unroll
  for (int i = 0; i < 16; ++i) {
    int idx = t + i * 256;
    int n = idx >> 5, c4 = idx & 31;
    int gn = nb + n;
    if (gn < NN) {
      float4 v = ((const float4*)x)[(size_t)gn * 32 + c4];
      ((uint2*)xh)[(size_t)gn * 32 + c4] =
          make_uint2(pack2(v.x, v.y), pack2(v.z, v.w));
    }
  }
  __syncthreads();  // wsl/wdl + cnt ready

  // ---- pass 1: coarse dst-binning (all blocks, CHX edges each)
  int e0 = blockIdx.x * CHX;
#pragma unroll
  for (int k = 0; k < CHX / 256; ++k) {
    int e = e0 + t + k * 256;
    if (e < ETOT) {
      int d = (e < EE) ? ei[EE + e] : (e - EE);
      atomicAdd(&cnt[d >> 8], 1);
    }
  }
  __syncthreads();
  for (int i = t; i < NBK; i += 256) {
    gbase[i] = (cnt[i] > 0) ? atomicAdd(&bcnt[i], cnt[i]) : 0;
    cnt[i] = 0;
  }
  __syncthreads();
#pragma unroll
  for (int k = 0; k < CHX / 256; ++k) {
    int e = e0 + t + k * 256;
    if (e < ETOT) {
      int s, d;
      if (e < EE) { s = ei[e]; d = ei[EE + e]; } else { s = d = e - EE; }
      int b = d >> 8;
      int idx = gbase[b] + atomicAdd(&cnt[b], 1);
      if (idx < CAP)
        ebuf[(size_t)b * CAP + idx] = (unsigned int)s | ((unsigned int)(d & 255) << 16);
    }
  }

  // ---- phase 2: a_s/a_d dots, 2 threads/node, x from global (L2-warm)
  {
    int n = t >> 1, half = t & 1;
    int gn = nb + n;
    if (gn < NN) {
      const float4* xp = (const float4*)x + (size_t)gn * 32 + half;
      float s0 = 0.f, s1 = 0.f, s2 = 0.f, s3 = 0.f;
      float d0 = 0.f, d1 = 0.f, d2 = 0.f, d3 = 0.f;
#pragma unroll
      for (int p = 0; p < 16; p += 4) {
        float4 v0 = xp[2 * p];
        float4 v1 = xp[2 * (p + 1)];
        float4 v2 = xp[2 * (p + 2)];
        float4 v3 = xp[2 * (p + 3)];
#define ACC(vv, pp)                                                        \
        {                                                                  \
          int c = 8 * (pp) + half * 4;                                     \
          float4 w0 = wsl[c], w1 = wsl[c + 1], w2 = wsl[c + 2], w3 = wsl[c + 3]; \
          s0 += vv.x * w0.x + vv.y * w1.x + vv.z * w2.x + vv.w * w3.x;     \
          s1 += vv.x * w0.y + vv.y * w1.y + vv.z * w2.y + vv.w * w3.y;     \
          s2 += vv.x * w0.z + vv.y * w1.z + vv.z * w2.z + vv.w * w3.z;     \
          s3 += vv.x * w0.w + vv.y * w1.w + vv.z * w2.w + vv.w * w3.w;     \
          float4 u0 = wdl[c], u1 = wdl[c + 1], u2 = wdl[c + 2], u3 = wdl[c + 3]; \
          d0 += vv.x * u0.x + vv.y * u1.x + vv.z * u2.x + vv.w * u3.x;     \
          d1 += vv.x * u0.y + vv.y * u1.y + vv.z * u2.y + vv.w * u3.y;     \
          d2 += vv.x * u0.z + vv.y * u1.z + vv.z * u2.z + vv.w * u3.z;     \
          d3 += vv.x * u0.w + vv.y * u1.w + vv.z * u2.w + vv.w * u3.w;     \
        }
        ACC(v0, p); ACC(v1, p + 1); ACC(v2, p + 2); ACC(v3, p + 3);
#undef ACC
      }
      s0 += __shfl_xor(s0, 1); s1 += __shfl_xor(s1, 1);
      s2 += __shfl_xor(s2, 1); s3 += __shfl_xor(s3, 1);
      d0 += __shfl_xor(d0, 1); d1 += __shfl_xor(d1, 1);
      d2 += __shfl_xor(d2, 1); d3 += __shfl_xor(d3, 1);
      if (half == 0) {
        *(float4*)(a_s + gn * 4) = make_float4(s0, s1, s2, s3);
        *(float4*)(a_d + gn * 4) = make_float4(d0, d1, d2, d3);
      }
    }
  }
}

// ---------------------------------------------------------------------------
// Pass 2: per 256-dst bucket -- local histogram, scan (writes rs), rank
// scatter in LDS, coalesced perm16.
// ---------------------------------------------------------------------------
__global__ __launch_bounds__(256) void k_p2(const unsigned int* __restrict__ ebuf,
                                            const int* __restrict__ bcnt,
                                            int* __restrict__ rs,
                                            unsigned short* __restrict__ perm16) {
  __shared__ int sb[256];
  __shared__ int loc[256];
  __shared__ int cnt[256];
  __shared__ unsigned short out16[CAP];
  __shared__ int basesh;
  int b = blockIdx.x, t = threadIdx.x;

  int v = (t < NBK) ? bcnt[t] : 0;
  sb[t] = v;
  __syncthreads();
  for (int off = 1; off < 256; off <<= 1) {
    int u = (t >= off) ? sb[t - off] : 0;
    __syncthreads();
    sb[t] += u;
    __syncthreads();
  }
  if (t == b) basesh = sb[t] - v;
  cnt[t] = 0;
  __syncthreads();

  int base = basesh;
  int m = min(bcnt[b], CAP);
  int d0 = b * 256;
  const unsigned int* rec = ebuf + (size_t)b * CAP;
  for (int i = t; i < m; i += 256) atomicAdd(&cnt[rec[i] >> 16], 1);
  __syncthreads();

  int c = cnt[t];
  sb[t] = c;
  __syncthreads();
  for (int off = 1; off < 256; off <<= 1) {
    int u = (t >= off) ? sb[t - off] : 0;
    __syncthreads();
    sb[t] += u;
    __syncthreads();
  }
  int ex = sb[t] - c;
  loc[t] = ex;
  int gi = d0 + t;
  if (gi < NN) rs[gi] = base + ex;
  if (b == NBK - 1 && t == 0) rs[NN] = base + m;
  cnt[t] = 0;
  __syncthreads();

  for (int i = t; i < m; i += 256) {
    unsigned int r = rec[i];
    int dl = r >> 16;
    int rk = atomicAdd(&cnt[dl], 1);
    out16[loc[dl] + rk] = (unsigned short)(r & 0xffffu);
  }
  __syncthreads();
  for (int i = t; i < m; i += 256) perm16[base + i] = out16[i];
}

// ---------------------------------------------------------------------------
// Aggregation in INPUT space: 128-thr blocks (2 waves), ONE node per wave.
// Weights single-shot (deg<=64). Denominator via redundant LDS-broadcast
// sum (independent ds_read_b128s) instead of a 24-op chained shfl butterfly.
// Batched b128 offset reads, 4-deep gather ILP. z written fp16 to global.
// ---------------------------------------------------------------------------
__global__ __launch_bounds__(128) void k_aggz(const float* __restrict__ a_s,
                                              const float* __restrict__ a_d,
                                              const unsigned int* __restrict__ xh,
                                              const int* __restrict__ rs,
                                              const unsigned short* __restrict__ perm16,
                                              unsigned int* __restrict__ zbuf) {
  __shared__ unsigned int off_s[AGW][MAXD];
  __shared__ float4 w_s[AGW][MAXD];
  int wave = threadIdx.x >> 6, lane = threadIdx.x & 63;
  int n = blockIdx.x * AGW + wave;
  float4 ad = *(const float4*)(a_d + n * 4);
  int s = rs[n], e = rs[n + 1];
  int deg = e - s;
  bool fast = (deg <= MAXD);

  float sc0, sc1, sc2, sc3;
  if (fast) {
    if (lane < deg) {
      int sn = perm16[s + lane];
      off_s[wave][lane] = (unsigned int)sn * 256u;  // byte offset into xh
      float4 as = *(const float4*)(a_s + sn * 4);
      float e0 = __expf(lrelu(as.x + ad.x));
      float e1 = __expf(lrelu(as.y + ad.y));
      float e2 = __expf(lrelu(as.z + ad.z));
      float e3 = __expf(lrelu(as.w + ad.w));
      w_s[wave][lane] = make_float4(e0, e1, e2, e3);
    }
    __builtin_amdgcn_wave_barrier();  // intra-wave LDS ordering fence
    // redundant broadcast sum: all lanes compute the same denominators via
    // independent (pipelined) LDS reads -- no cross-lane dependency chain.
    float t0 = 0.f, t1 = 0.f, t2 = 0.f, t3 = 0.f;
    int j = 0;
    for (; j + 4 <= deg; j += 4) {
      float4 a0 = w_s[wave][j],     a1 = w_s[wave][j + 1];
      float4 a2 = w_s[wave][j + 2], a3 = w_s[wave][j + 3];
      t0 += (a0.x + a1.x) + (a2.x + a3.x);
      t1 += (a0.y + a1.y) + (a2.y + a3.y);
      t2 += (a0.z + a1.z) + (a2.z + a3.z);
      t3 += (a0.w + a1.w) + (a2.w + a3.w);
    }
    for (; j < deg; ++j) {
      float4 a0 = w_s[wave][j];
      t0 += a0.x; t1 += a0.y; t2 += a0.z; t3 += a0.w;
    }
    sc0 = 0.25f / (t0 + 1e-16f); sc1 = 0.25f / (t1 + 1e-16f);
    sc2 = 0.25f / (t2 + 1e-16f); sc3 = 0.25f / (t3 + 1e-16f);
  } else {
    float t0 = 0.f, t1 = 0.f, t2 = 0.f, t3 = 0.f;
    for (int j = lane; j < deg; j += 64) {
      int sn = perm16[s + j];
      float4 as = *(const float4*)(a_s + sn * 4);
      t0 += __expf(lrelu(as.x + ad.x)); t1 += __expf(lrelu(as.y + ad.y));
      t2 += __expf(lrelu(as.z + ad.z)); t3 += __expf(lrelu(as.w + ad.w));
    }
#pragma unroll
    for (int off = 32; off; off >>= 1) {
      t0 += __shfl_xor(t0, off); t1 += __shfl_xor(t1, off);
      t2 += __shfl_xor(t2, off); t3 += __shfl_xor(t3, off);
    }
    sc0 = 0.25f / (t0 + 1e-16f); sc1 = 0.25f / (t1 + 1e-16f);
    sc2 = 0.25f / (t2 + 1e-16f); sc3 = 0.25f / (t3 + 1e-16f);
  }

  const char* xb = (const char*)xh;
  int lb = lane * 4;
  f32x2 za0 = {0.f, 0.f}, za1 = {0.f, 0.f}, za2 = {0.f, 0.f}, za3 = {0.f, 0.f};
  if (fast) {
    int j = 0;
    for (; j + 4 <= deg; j += 4) {
      u32x4 ov = *(const u32x4*)&off_s[wave][j];   // one b128: 4 offsets
      unsigned int u0 = *(const unsigned int*)(xb + ov[0] + lb);
      unsigned int u1 = *(const unsigned int*)(xb + ov[1] + lb);
      unsigned int u2 = *(const unsigned int*)(xb + ov[2] + lb);
      unsigned int u3 = *(const unsigned int*)(xb + ov[3] + lb);
      float4 w0 = w_s[wave][j],     w1 = w_s[wave][j + 1];
      float4 w2 = w_s[wave][j + 2], w3 = w_s[wave][j + 3];
      f16x2 p0 = __builtin_bit_cast(f16x2, u0);
      f16x2 p1 = __builtin_bit_cast(f16x2, u1);
      f16x2 p2 = __builtin_bit_cast(f16x2, u2);
      f16x2 p3 = __builtin_bit_cast(f16x2, u3);
      f32x2 x0 = {(float)p0[0], (float)p0[1]};
      f32x2 x1 = {(float)p1[0], (float)p1[1]};
      f32x2 x2 = {(float)p2[0], (float)p2[1]};
      f32x2 x3 = {(float)p3[0], (float)p3[1]};
      za0 += w0.x * x0; za1 += w0.y * x0; za2 += w0.z * x0; za3 += w0.w * x0;
      za0 += w1.x * x1; za1 += w1.y * x1; za2 += w1.z * x1; za3 += w1.w * x1;
      za0 += w2.x * x2; za1 += w2.y * x2; za2 += w2.z * x2; za3 += w2.w * x2;
      za0 += w3.x * x3; za1 += w3.y * x3; za2 += w3.z * x3; za3 += w3.w * x3;
    }
    for (; j < deg; ++j) {
      float4 w = w_s[wave][j];
      unsigned int u = *(const unsigned int*)(xb + off_s[wave][j] + lb);
      f16x2 p = __builtin_bit_cast(f16x2, u);
      f32x2 xv = {(float)p[0], (float)p[1]};
      za0 += w.x * xv; za1 += w.y * xv; za2 += w.z * xv; za3 += w.w * xv;
    }
  } else {
    for (int j = 0; j < deg; ++j) {
      int sn = perm16[s + j];
      float4 as = *(const float4*)(a_s + sn * 4);
      float w0 = __expf(lrelu(as.x + ad.x));
      float w1 = __expf(lrelu(as.y + ad.y));
      float w2 = __expf(lrelu(as.z + ad.z));
      float w3 = __expf(lrelu(as.w + ad.w));
      unsigned int u = xh[sn * 64 + lane];
      f16x2 p = __builtin_bit_cast(f16x2, u);
      f32x2 xv = {(float)p[0], (float)p[1]};
      za0 += w0 * xv; za1 += w1 * xv; za2 += w2 * xv; za3 += w3 * xv;
    }
  }

  zbuf[n * 256 + 0 * 64 + lane] = pack2(za0[0] * sc0, za0[1] * sc0);
  zbuf[n * 256 + 1 * 64 + lane] = pack2(za1[0] * sc1, za1[1] * sc1);
  zbuf[n * 256 + 2 * 64 + lane] = pack2(za2[0] * sc2, za2[1] * sc2);
  zbuf[n * 256 + 3 * 64 + lane] = pack2(za3[0] * sc3, za3[1] * sc3);
}

// ---------------------------------------------------------------------------
// GEMM: out[N][128] fp32 = Z[N][512] (fp16) @ Bt^T, MFMA 16x16x32 f16.
// Block tile 64x128, 4 waves (2x2 of 32x64), K staged 128/step, swizzled LDS.
// ---------------------------------------------------------------------------
__global__ __launch_bounds__(256) void k_gemmz(const unsigned short* __restrict__ zbuf,
                                               const unsigned short* __restrict__ Bt,
                                               float* __restrict__ out) {
  __shared__ u32x4 Al[1024];
  __shared__ u32x4 Bl[2048];
  int m0 = blockIdx.x * 64;
  int wave = threadIdx.x >> 6, lane = threadIdx.x & 63;
  int wm = (wave >> 1) * 32, wn = (wave & 1) * 64;
  int lr = lane & 15, lk = lane >> 4;

  f32x4 acc[2][4];
#pragma unroll
  for (int mi = 0; mi < 2; ++mi)
#pragma unroll
    for (int ni = 0; ni < 4; ++ni) acc[mi][ni] = (f32x4){0.f, 0.f, 0.f, 0.f};

  for (int t = 0; t < 4; ++t) {
#pragma unroll
    for (int i = 0; i < 4; ++i) {
      int id = threadIdx.x + 256 * i;
      int row = id >> 4, kc = id & 15;
      int grow = m0 + row;
      u32x4 v = {0u, 0u, 0u, 0u};
      if (grow < NN) v = *(const u32x4*)((const char*)zbuf + grow * 1024 + t * 256 + kc * 16);
      Al[row * 16 + (kc ^ (row & 7))] = v;
    }
#pragma unroll
    for (int i = 0; i < 8; ++i) {
      int id = threadIdx.x + 256 * i;
      int col = id >> 4, kc = id & 15;
      u32x4 v = *(const u32x4*)((const char*)Bt + col * 1024 + t * 256 + kc * 16);
      Bl[col * 16 + (kc ^ (col & 7))] = v;
    }
    __syncthreads();
#pragma unroll
    for (int ks = 0; ks < 4; ++ks) {
      f16x8 af[2], bf[4];
#pragma unroll
      for (int mi = 0; mi < 2; ++mi) {
        int r = wm + mi * 16 + lr;
        af[mi] = __builtin_bit_cast(f16x8, Al[r * 16 + ((ks * 4 + lk) ^ (r & 7))]);
      }
#pragma unroll
      for (int ni = 0; ni < 4; ++ni) {
        int c = wn + ni * 16 + lr;
        bf[ni] = __builtin_bit_cast(f16x8, Bl[c * 16 + ((ks * 4 + lk) ^ (c & 7))]);
      }
#pragma unroll
      for (int mi = 0; mi < 2; ++mi)
#pragma unroll
        for (int ni = 0; ni < 4; ++ni)
          acc[mi][ni] = __builtin_amdgcn_mfma_f32_16x16x32_f16(af[mi], bf[ni], acc[mi][ni], 0, 0, 0);
    }
    __syncthreads();
  }

  int cr = lk * 4;
#pragma unroll
  for (int mi = 0; mi < 2; ++mi) {
#pragma unroll
    for (int j = 0; j < 4; ++j) {
      int row = m0 + wm + mi * 16 + cr + j;
      if (row < NN) {
#pragma unroll
        for (int ni = 0; ni < 4; ++ni) {
          int col = wn + ni * 16 + lr;
          out[row * 128 + col] = acc[mi][ni][j];
        }
      }
    }
  }
}

// ---------------------------------------------------------------------------
extern "C" void kernel_launch(void* const* d_in, const int* in_sizes, int n_in,
                              void* d_out, int out_size, void* d_ws, size_t ws_size,
                              hipStream_t stream) {
  const float* x = (const float*)d_in[0];
  const int* ei = (const int*)d_in[1];
  const float* W = (const float*)d_in[2];
  const float* att_s = (const float*)d_in[3];
  const float* att_d = (const float*)d_in[4];
  float* out = (float*)d_out;
  char* ws = (char*)d_ws;

  unsigned int* xh = (unsigned int*)(ws + 0);                 // 12,800,000 B
  unsigned int* zbuf = (unsigned int*)(ws + 12800000);        // 51,200,000 B
  unsigned int* ebuf = (unsigned int*)(ws + 12800000);        //  4,816,896 B (aliased; dead before zbuf)
  unsigned short* Bt = (unsigned short*)(ws + 64000000);      //    131,072 B
  float* WaS = (float*)(ws + 64131072);                       //      2,048 B
  float* WaD = (float*)(ws + 64133120);                       //      2,048 B
  float* a_s = (float*)(ws + 64135168);                       //    800,000 B
  float* a_d = (float*)(ws + 64935168);                       //    800,000 B
  int* rs = (int*)(ws + 65735168);                            //    200,192 B
  int* bcnt = (int*)(ws + 65935360);                          //      1,024 B
  unsigned short* perm16 = (unsigned short*)(ws + 65936384);  //  1,700,000 B

  k_prep<<<256, 256, 0, stream>>>(W, att_s, att_d, Bt, WaS, WaD, bcnt);
  k_xcast_p1<<<(NN + 127) / 128, 256, 0, stream>>>(x, WaS, WaD, ei, xh, a_s, a_d, bcnt, ebuf);
  k_p2<<<NBK, 256, 0, stream>>>(ebuf, bcnt, rs, perm16);
  k_aggz<<<NN / AGW, 128, 0, stream>>>(a_s, a_d, xh, rs, perm16, zbuf);
  k_gemmz<<<(NN + 63) / 64, 256, 0, stream>>>((const unsigned short*)zbuf, Bt, out);
}

// Round 14
// 116.710 us; speedup vs baseline: 1.0132x; 1.0132x over previous
//
#include <hip/hip_runtime.h>

#define NN 50000
#define EE 800000
#define ETOT (EE + NN)
#define MAXD 64      // max degree on fast path (Poisson(16)+1 -> max ~45)
#define NBK 196      // dst buckets of 256 nodes
#define CAP 6144     // records per bucket slot (mean 4352)
#define CHX 2304     // edges per xcast block (9*256); 391 blocks cover ETOT
#define AGW 2        // waves per aggz block

typedef _Float16 f16x8 __attribute__((ext_vector_type(8)));
typedef _Float16 f16x2 __attribute__((ext_vector_type(2)));
typedef float f32x4 __attribute__((ext_vector_type(4)));
typedef float f32x2 __attribute__((ext_vector_type(2)));
typedef unsigned int u32x4 __attribute__((ext_vector_type(4)));

__device__ __forceinline__ float lrelu(float v) { return v > 0.f ? v : 0.2f * v; }
__device__ __forceinline__ unsigned int pack2(float a, float b) {
  unsigned short lo = __builtin_bit_cast(unsigned short, (_Float16)a);
  unsigned short hi = __builtin_bit_cast(unsigned short, (_Float16)b);
  return (unsigned int)lo | ((unsigned int)hi << 16);
}

// ---------------------------------------------------------------------------
// Prep: Bt[col][k] fp16 (k = h*128+c), folded attention WaS/WaD, zero bcnt.
// ---------------------------------------------------------------------------
__global__ void k_prep(const float* __restrict__ W,
                       const float* __restrict__ att_s,
                       const float* __restrict__ att_d,
                       unsigned short* __restrict__ Bt,
                       float* __restrict__ WaS, float* __restrict__ WaD,
                       int* __restrict__ bcnt) {
  int gid = blockIdx.x * blockDim.x + threadIdx.x;
  if (gid < NBK) bcnt[gid] = 0;
  if (gid < 128 * 512) {
    int col = gid >> 9, k = gid & 511;
    float v = W[(k & 127) * 512 + (k >> 7) * 128 + col];
    _Float16 hv = (_Float16)v;
    Bt[col * 512 + k] = __builtin_bit_cast(unsigned short, hv);
  }
  if (gid < 512) {
    int k = gid >> 2, h = gid & 3;
    const float* wrow = W + k * 512 + h * 128;
    const float* as = att_s + h * 128;
    const float* ad = att_d + h * 128;
    float ss = 0.f, sd = 0.f;
    for (int c = 0; c < 128; ++c) { float w = wrow[c]; ss += w * as[c]; sd += w * ad[c]; }
    WaS[k * 4 + h] = ss;
    WaD[k * 4 + h] = sd;
  }
}

// ---------------------------------------------------------------------------
// Fused: x->fp16 xh, pass-1 coarse binning (spread over all blocks), then
// a_s/a_d dot products reading x straight from global (L2-warm).
// ---------------------------------------------------------------------------
__global__ __launch_bounds__(256) void k_xcast_p1(const float* __restrict__ x,
                                                  const float* __restrict__ WaS,
                                                  const float* __restrict__ WaD,
                                                  const int* __restrict__ ei,
                                                  unsigned int* __restrict__ xh,
                                                  float* __restrict__ a_s,
                                                  float* __restrict__ a_d,
                                                  int* __restrict__ bcnt,
                                                  unsigned int* __restrict__ ebuf) {
  __shared__ float4 wsl[128];
  __shared__ float4 wdl[128];
  __shared__ int cnt[NBK];
  __shared__ int gbase[NBK];
  int t = threadIdx.x;
  int nb = blockIdx.x * 128;
  if (t < 128) wsl[t] = ((const float4*)WaS)[t];
  else wdl[t - 128] = ((const float4*)WaD)[t - 128];
  for (int i = t; i < NBK; i += 256) cnt[i] = 0;

  // ---- phase 1: x -> fp16 xh (streaming, no LDS)
#pragma unroll
  for (int i = 0; i < 16; ++i) {
    int idx = t + i * 256;
    int n = idx >> 5, c4 = idx & 31;
    int gn = nb + n;
    if (gn < NN) {
      float4 v = ((const float4*)x)[(size_t)gn * 32 + c4];
      ((uint2*)xh)[(size_t)gn * 32 + c4] =
          make_uint2(pack2(v.x, v.y), pack2(v.z, v.w));
    }
  }
  __syncthreads();  // wsl/wdl + cnt ready

  // ---- pass 1: coarse dst-binning (all blocks, CHX edges each)
  int e0 = blockIdx.x * CHX;
#pragma unroll
  for (int k = 0; k < CHX / 256; ++k) {
    int e = e0 + t + k * 256;
    if (e < ETOT) {
      int d = (e < EE) ? ei[EE + e] : (e - EE);
      atomicAdd(&cnt[d >> 8], 1);
    }
  }
  __syncthreads();
  for (int i = t; i < NBK; i += 256) {
    gbase[i] = (cnt[i] > 0) ? atomicAdd(&bcnt[i], cnt[i]) : 0;
    cnt[i] = 0;
  }
  __syncthreads();
#pragma unroll
  for (int k = 0; k < CHX / 256; ++k) {
    int e = e0 + t + k * 256;
    if (e < ETOT) {
      int s, d;
      if (e < EE) { s = ei[e]; d = ei[EE + e]; } else { s = d = e - EE; }
      int b = d >> 8;
      int idx = gbase[b] + atomicAdd(&cnt[b], 1);
      if (idx < CAP)
        ebuf[(size_t)b * CAP + idx] = (unsigned int)s | ((unsigned int)(d & 255) << 16);
    }
  }

  // ---- phase 2: a_s/a_d dots, 2 threads/node, x from global (L2-warm)
  {
    int n = t >> 1, half = t & 1;
    int gn = nb + n;
    if (gn < NN) {
      const float4* xp = (const float4*)x + (size_t)gn * 32 + half;
      float s0 = 0.f, s1 = 0.f, s2 = 0.f, s3 = 0.f;
      float d0 = 0.f, d1 = 0.f, d2 = 0.f, d3 = 0.f;
#pragma unroll
      for (int p = 0; p < 16; p += 4) {
        float4 v0 = xp[2 * p];
        float4 v1 = xp[2 * (p + 1)];
        float4 v2 = xp[2 * (p + 2)];
        float4 v3 = xp[2 * (p + 3)];
#define ACC(vv, pp)                                                        \
        {                                                                  \
          int c = 8 * (pp) + half * 4;                                     \
          float4 w0 = wsl[c], w1 = wsl[c + 1], w2 = wsl[c + 2], w3 = wsl[c + 3]; \
          s0 += vv.x * w0.x + vv.y * w1.x + vv.z * w2.x + vv.w * w3.x;     \
          s1 += vv.x * w0.y + vv.y * w1.y + vv.z * w2.y + vv.w * w3.y;     \
          s2 += vv.x * w0.z + vv.y * w1.z + vv.z * w2.z + vv.w * w3.z;     \
          s3 += vv.x * w0.w + vv.y * w1.w + vv.z * w2.w + vv.w * w3.w;     \
          float4 u0 = wdl[c], u1 = wdl[c + 1], u2 = wdl[c + 2], u3 = wdl[c + 3]; \
          d0 += vv.x * u0.x + vv.y * u1.x + vv.z * u2.x + vv.w * u3.x;     \
          d1 += vv.x * u0.y + vv.y * u1.y + vv.z * u2.y + vv.w * u3.y;     \
          d2 += vv.x * u0.z + vv.y * u1.z + vv.z * u2.z + vv.w * u3.z;     \
          d3 += vv.x * u0.w + vv.y * u1.w + vv.z * u2.w + vv.w * u3.w;     \
        }
        ACC(v0, p); ACC(v1, p + 1); ACC(v2, p + 2); ACC(v3, p + 3);
#undef ACC
      }
      s0 += __shfl_xor(s0, 1); s1 += __shfl_xor(s1, 1);
      s2 += __shfl_xor(s2, 1); s3 += __shfl_xor(s3, 1);
      d0 += __shfl_xor(d0, 1); d1 += __shfl_xor(d1, 1);
      d2 += __shfl_xor(d2, 1); d3 += __shfl_xor(d3, 1);
      if (half == 0) {
        *(float4*)(a_s + gn * 4) = make_float4(s0, s1, s2, s3);
        *(float4*)(a_d + gn * 4) = make_float4(d0, d1, d2, d3);
      }
    }
  }
}

// ---------------------------------------------------------------------------
// Pass 2: per 256-dst bucket -- local histogram, scan (writes rs), rank
// scatter in LDS, coalesced perm16.
// ---------------------------------------------------------------------------
__global__ __launch_bounds__(256) void k_p2(const unsigned int* __restrict__ ebuf,
                                            const int* __restrict__ bcnt,
                                            int* __restrict__ rs,
                                            unsigned short* __restrict__ perm16) {
  __shared__ int sb[256];
  __shared__ int loc[256];
  __shared__ int cnt[256];
  __shared__ unsigned short out16[CAP];
  __shared__ int basesh;
  int b = blockIdx.x, t = threadIdx.x;

  int v = (t < NBK) ? bcnt[t] : 0;
  sb[t] = v;
  __syncthreads();
  for (int off = 1; off < 256; off <<= 1) {
    int u = (t >= off) ? sb[t - off] : 0;
    __syncthreads();
    sb[t] += u;
    __syncthreads();
  }
  if (t == b) basesh = sb[t] - v;
  cnt[t] = 0;
  __syncthreads();

  int base = basesh;
  int m = min(bcnt[b], CAP);
  int d0 = b * 256;
  const unsigned int* rec = ebuf + (size_t)b * CAP;
  for (int i = t; i < m; i += 256) atomicAdd(&cnt[rec[i] >> 16], 1);
  __syncthreads();

  int c = cnt[t];
  sb[t] = c;
  __syncthreads();
  for (int off = 1; off < 256; off <<= 1) {
    int u = (t >= off) ? sb[t - off] : 0;
    __syncthreads();
    sb[t] += u;
    __syncthreads();
  }
  int ex = sb[t] - c;
  loc[t] = ex;
  int gi = d0 + t;
  if (gi < NN) rs[gi] = base + ex;
  if (b == NBK - 1 && t == 0) rs[NN] = base + m;
  cnt[t] = 0;
  __syncthreads();

  for (int i = t; i < m; i += 256) {
    unsigned int r = rec[i];
    int dl = r >> 16;
    int rk = atomicAdd(&cnt[dl], 1);
    out16[loc[dl] + rk] = (unsigned short)(r & 0xffffu);
  }
  __syncthreads();
  for (int i = t; i < m; i += 256) perm16[base + i] = out16[i];
}

// ---------------------------------------------------------------------------
// Aggregation in INPUT space: 128-thr blocks (2 waves), ONE node per wave,
// grid 25000 -> 32 waves/CU cap + fine-grained scheduling. Weights
// single-shot (deg<=64), batched b128 offset reads, 4-deep gather ILP.
// ---------------------------------------------------------------------------
__global__ __launch_bounds__(128) void k_aggz(const float* __restrict__ a_s,
                                              const float* __restrict__ a_d,
                                              const unsigned int* __restrict__ xh,
                                              const int* __restrict__ rs,
                                              const unsigned short* __restrict__ perm16,
                                              unsigned int* __restrict__ zbuf) {
  __shared__ unsigned int off_s[AGW][MAXD];
  __shared__ float4 w_s[AGW][MAXD];
  int wave = threadIdx.x >> 6, lane = threadIdx.x & 63;
  int n = blockIdx.x * AGW + wave;
  float4 ad = *(const float4*)(a_d + n * 4);
  int s = rs[n], e = rs[n + 1];
  int deg = e - s;
  bool fast = (deg <= MAXD);

  float t0 = 0.f, t1 = 0.f, t2 = 0.f, t3 = 0.f;
  if (fast) {
    if (lane < deg) {
      int sn = perm16[s + lane];
      off_s[wave][lane] = (unsigned int)sn * 256u;  // byte offset into xh
      float4 as = *(const float4*)(a_s + sn * 4);
      float e0 = __expf(lrelu(as.x + ad.x));
      float e1 = __expf(lrelu(as.y + ad.y));
      float e2 = __expf(lrelu(as.z + ad.z));
      float e3 = __expf(lrelu(as.w + ad.w));
      w_s[wave][lane] = make_float4(e0, e1, e2, e3);
      t0 = e0; t1 = e1; t2 = e2; t3 = e3;
    }
  } else {
    for (int j = lane; j < deg; j += 64) {
      int sn = perm16[s + j];
      float4 as = *(const float4*)(a_s + sn * 4);
      t0 += __expf(lrelu(as.x + ad.x)); t1 += __expf(lrelu(as.y + ad.y));
      t2 += __expf(lrelu(as.z + ad.z)); t3 += __expf(lrelu(as.w + ad.w));
    }
  }
#pragma unroll
  for (int off = 32; off; off >>= 1) {
    t0 += __shfl_xor(t0, off); t1 += __shfl_xor(t1, off);
    t2 += __shfl_xor(t2, off); t3 += __shfl_xor(t3, off);
  }
  float sc0 = 0.25f / (t0 + 1e-16f), sc1 = 0.25f / (t1 + 1e-16f);
  float sc2 = 0.25f / (t2 + 1e-16f), sc3 = 0.25f / (t3 + 1e-16f);
  __builtin_amdgcn_wave_barrier();  // intra-wave LDS ordering fence

  const char* xb = (const char*)xh;
  int lb = lane * 4;
  f32x2 za0 = {0.f, 0.f}, za1 = {0.f, 0.f}, za2 = {0.f, 0.f}, za3 = {0.f, 0.f};
  if (fast) {
    int j = 0;
    for (; j + 4 <= deg; j += 4) {
      u32x4 ov = *(const u32x4*)&off_s[wave][j];   // one b128: 4 offsets
      unsigned int u0 = *(const unsigned int*)(xb + ov[0] + lb);
      unsigned int u1 = *(const unsigned int*)(xb + ov[1] + lb);
      unsigned int u2 = *(const unsigned int*)(xb + ov[2] + lb);
      unsigned int u3 = *(const unsigned int*)(xb + ov[3] + lb);
      float4 w0 = w_s[wave][j],     w1 = w_s[wave][j + 1];
      float4 w2 = w_s[wave][j + 2], w3 = w_s[wave][j + 3];
      f16x2 p0 = __builtin_bit_cast(f16x2, u0);
      f16x2 p1 = __builtin_bit_cast(f16x2, u1);
      f16x2 p2 = __builtin_bit_cast(f16x2, u2);
      f16x2 p3 = __builtin_bit_cast(f16x2, u3);
      f32x2 x0 = {(float)p0[0], (float)p0[1]};
      f32x2 x1 = {(float)p1[0], (float)p1[1]};
      f32x2 x2 = {(float)p2[0], (float)p2[1]};
      f32x2 x3 = {(float)p3[0], (float)p3[1]};
      za0 += w0.x * x0; za1 += w0.y * x0; za2 += w0.z * x0; za3 += w0.w * x0;
      za0 += w1.x * x1; za1 += w1.y * x1; za2 += w1.z * x1; za3 += w1.w * x1;
      za0 += w2.x * x2; za1 += w2.y * x2; za2 += w2.z * x2; za3 += w2.w * x2;
      za0 += w3.x * x3; za1 += w3.y * x3; za2 += w3.z * x3; za3 += w3.w * x3;
    }
    for (; j < deg; ++j) {
      float4 w = w_s[wave][j];
      unsigned int u = *(const unsigned int*)(xb + off_s[wave][j] + lb);
      f16x2 p = __builtin_bit_cast(f16x2, u);
      f32x2 xv = {(float)p[0], (float)p[1]};
      za0 += w.x * xv; za1 += w.y * xv; za2 += w.z * xv; za3 += w.w * xv;
    }
  } else {
    for (int j = 0; j < deg; ++j) {
      int sn = perm16[s + j];
      float4 as = *(const float4*)(a_s + sn * 4);
      float w0 = __expf(lrelu(as.x + ad.x));
      float w1 = __expf(lrelu(as.y + ad.y));
      float w2 = __expf(lrelu(as.z + ad.z));
      float w3 = __expf(lrelu(as.w + ad.w));
      unsigned int u = xh[sn * 64 + lane];
      f16x2 p = __builtin_bit_cast(f16x2, u);
      f32x2 xv = {(float)p[0], (float)p[1]};
      za0 += w0 * xv; za1 += w1 * xv; za2 += w2 * xv; za3 += w3 * xv;
    }
  }

  zbuf[n * 256 + 0 * 64 + lane] = pack2(za0[0] * sc0, za0[1] * sc0);
  zbuf[n * 256 + 1 * 64 + lane] = pack2(za1[0] * sc1, za1[1] * sc1);
  zbuf[n * 256 + 2 * 64 + lane] = pack2(za2[0] * sc2, za2[1] * sc2);
  zbuf[n * 256 + 3 * 64 + lane] = pack2(za3[0] * sc3, za3[1] * sc3);
}

// ---------------------------------------------------------------------------
// GEMM: out[N][128] fp32 = Z[N][512] (fp16) @ Bt^T, MFMA 16x16x32 f16.
// Block tile 64x128, 4 waves (2x2 of 32x64), K staged 128/step, swizzled LDS.
// ---------------------------------------------------------------------------
__global__ __launch_bounds__(256) void k_gemmz(const unsigned short* __restrict__ zbuf,
                                               const unsigned short* __restrict__ Bt,
                                               float* __restrict__ out) {
  __shared__ u32x4 Al[1024];
  __shared__ u32x4 Bl[2048];
  int m0 = blockIdx.x * 64;
  int wave = threadIdx.x >> 6, lane = threadIdx.x & 63;
  int wm = (wave >> 1) * 32, wn = (wave & 1) * 64;
  int lr = lane & 15, lk = lane >> 4;

  f32x4 acc[2][4];
#pragma unroll
  for (int mi = 0; mi < 2; ++mi)
#pragma unroll
    for (int ni = 0; ni < 4; ++ni) acc[mi][ni] = (f32x4){0.f, 0.f, 0.f, 0.f};

  for (int t = 0; t < 4; ++t) {
#pragma unroll
    for (int i = 0; i < 4; ++i) {
      int id = threadIdx.x + 256 * i;
      int row = id >> 4, kc = id & 15;
      int grow = m0 + row;
      u32x4 v = {0u, 0u, 0u, 0u};
      if (grow < NN) v = *(const u32x4*)((const char*)zbuf + grow * 1024 + t * 256 + kc * 16);
      Al[row * 16 + (kc ^ (row & 7))] = v;
    }
#pragma unroll
    for (int i = 0; i < 8; ++i) {
      int id = threadIdx.x + 256 * i;
      int col = id >> 4, kc = id & 15;
      u32x4 v = *(const u32x4*)((const char*)Bt + col * 1024 + t * 256 + kc * 16);
      Bl[col * 16 + (kc ^ (col & 7))] = v;
    }
    __syncthreads();
#pragma unroll
    for (int ks = 0; ks < 4; ++ks) {
      f16x8 af[2], bf[4];
#pragma unroll
      for (int mi = 0; mi < 2; ++mi) {
        int r = wm + mi * 16 + lr;
        af[mi] = __builtin_bit_cast(f16x8, Al[r * 16 + ((ks * 4 + lk) ^ (r & 7))]);
      }
#pragma unroll
      for (int ni = 0; ni < 4; ++ni) {
        int c = wn + ni * 16 + lr;
        bf[ni] = __builtin_bit_cast(f16x8, Bl[c * 16 + ((ks * 4 + lk) ^ (c & 7))]);
      }
#pragma unroll
      for (int mi = 0; mi < 2; ++mi)
#pragma unroll
        for (int ni = 0; ni < 4; ++ni)
          acc[mi][ni] = __builtin_amdgcn_mfma_f32_16x16x32_f16(af[mi], bf[ni], acc[mi][ni], 0, 0, 0);
    }
    __syncthreads();
  }

  int cr = lk * 4;
#pragma unroll
  for (int mi = 0; mi < 2; ++mi) {
#pragma unroll
    for (int j = 0; j < 4; ++j) {
      int row = m0 + wm + mi * 16 + cr + j;
      if (row < NN) {
#pragma unroll
        for (int ni = 0; ni < 4; ++ni) {
          int col = wn + ni * 16 + lr;
          out[row * 128 + col] = acc[mi][ni][j];
        }
      }
    }
  }
}

// ---------------------------------------------------------------------------
extern "C" void kernel_launch(void* const* d_in, const int* in_sizes, int n_in,
                              void* d_out, int out_size, void* d_ws, size_t ws_size,
                              hipStream_t stream) {
  const float* x = (const float*)d_in[0];
  const int* ei = (const int*)d_in[1];
  const float* W = (const float*)d_in[2];
  const float* att_s = (const float*)d_in[3];
  const float* att_d = (const float*)d_in[4];
  float* out = (float*)d_out;
  char* ws = (char*)d_ws;

  unsigned int* xh = (unsigned int*)(ws + 0);                 // 12,800,000 B
  unsigned int* zbuf = (unsigned int*)(ws + 12800000);        // 51,200,000 B
  unsigned int* ebuf = (unsigned int*)(ws + 12800000);        //  4,816,896 B (aliased; dead before zbuf)
  unsigned short* Bt = (unsigned short*)(ws + 64000000);      //    131,072 B
  float* WaS = (float*)(ws + 64131072);                       //      2,048 B
  float* WaD = (float*)(ws + 64133120);                       //      2,048 B
  float* a_s = (float*)(ws + 64135168);                       //    800,000 B
  float* a_d = (float*)(ws + 64935168);                       //    800,000 B
  int* rs = (int*)(ws + 65735168);                            //    200,192 B
  int* bcnt = (int*)(ws + 65935360);                          //      1,024 B
  unsigned short* perm16 = (unsigned short*)(ws + 65936384);  //  1,700,000 B

  k_prep<<<256, 256, 0, stream>>>(W, att_s, att_d, Bt, WaS, WaD, bcnt);
  k_xcast_p1<<<(NN + 127) / 128, 256, 0, stream>>>(x, WaS, WaD, ei, xh, a_s, a_d, bcnt, ebuf);
  k_p2<<<NBK, 256, 0, stream>>>(ebuf, bcnt, rs, perm16);
  k_aggz<<<NN / AGW, 128, 0, stream>>>(a_s, a_d, xh, rs, perm16, zbuf);
  k_gemmz<<<(NN + 63) / 64, 256, 0, stream>>>((const unsigned short*)zbuf, Bt, out);
}